// Round 3
// baseline (495.163 us; speedup 1.0000x reference)
//
#include <hip/hip_runtime.h>
#include <math.h>

#define NUM_CLASSES 81
#define ROWS 64
#define ELEMS (ROWS * NUM_CLASSES)        // 5184 floats (scores) / float4s (boxes) per block
#define VECS  (ELEMS / 4)                 // 1296 float4s of logits/scores per block
#define LVEC_ITERS (VECS / 256)           // 5, remainder 16
#define LVEC_REM   (VECS - LVEC_ITERS * 256)
#define BOX_ITERS  (ELEMS / 256)          // 20, remainder 64
#define BOX_REM    (ELEMS - BOX_ITERS * 256)

typedef float vfloat4 __attribute__((ext_vector_type(4)));

__device__ __forceinline__ float4 decode_clip(const float4 b, const float4 r,
                                              const float wmax, const float hmax)
{
    const float BBOX_XFORM_CLIP = 4.135166556742356f; // log(1000/16)
    const float w  = b.z - b.x + 1.0f;
    const float h  = b.w - b.y + 1.0f;
    const float cx = b.x + 0.5f * w;
    const float cy = b.y + 0.5f * h;
    const float dx = r.x * 0.1f;
    const float dy = r.y * 0.1f;
    const float dw = fminf(r.z * 0.2f, BBOX_XFORM_CLIP);
    const float dh = fminf(r.w * 0.2f, BBOX_XFORM_CLIP);
    const float px = dx * w + cx;
    const float py = dy * h + cy;
    const float pw = expf(dw) * w;
    const float ph = expf(dh) * h;
    const float x1 = fminf(fmaxf(px - 0.5f * pw, 0.0f), wmax);
    const float y1 = fminf(fmaxf(py - 0.5f * ph, 0.0f), hmax);
    const float x2 = fminf(fmaxf(px + 0.5f * pw - 1.0f, 0.0f), wmax);
    const float y2 = fminf(fmaxf(py + 0.5f * ph - 1.0f, 0.0f), hmax);
    return make_float4(x1, y1, x2, y2);
}

// lgkmcnt(0)-only barrier: orders LDS writes->reads across the block WITHOUT
// draining vmcnt, so in-flight global loads/stores survive the barrier.
// All consumers on the far side are memory ops (ds_read/global_store), so the
// "memory" clobber orders them; sched_barrier(0) pins against hoisting.
__device__ __forceinline__ void lds_barrier()
{
    asm volatile("s_waitcnt lgkmcnt(0)" ::: "memory");
    __builtin_amdgcn_s_barrier();
    __builtin_amdgcn_sched_barrier(0);
}

// One 256-thread block = 64 rows.
//  A: issue 5-6 float4 logits loads per thread into REGISTERS (vmcnt in flight)
//  B: threads 0..63 decode boxes -> LDS; lgkm-only barrier (loads NOT drained)
//  C: stream 5184 box float4 NT stores (hides the logits load latency)
//  D: registers -> LDS; lgkm-only barrier
//  E: softmax, 4 lanes per row (2 shuffle rounds); lgkm-only barrier
//  F: stream 1296 score float4 NT stores
__global__ __launch_bounds__(256) void fused_kernel(
    const float* __restrict__ logits,
    const float4* __restrict__ box_reg4,
    const float4* __restrict__ prop4,
    const int* __restrict__ img_w_p,
    const int* __restrict__ img_h_p,
    float* __restrict__ out_boxes,
    float* __restrict__ out_scores,
    int N)
{
    __shared__ float lds_val[ELEMS];          // logits, then scores (in place)
    __shared__ float4 lds_box[ROWS];
    vfloat4* lds4 = (vfloat4*)lds_val;

    const int tid  = threadIdx.x;
    const int row0 = blockIdx.x * ROWS;
    if (row0 >= N) return;
    const int rows = min(ROWS, N - row0);

    // wave-uniform scalar loads (same for every thread)
    const float wmax = (float)(*img_w_p) - 1.0f;
    const float hmax = (float)(*img_h_p) - 1.0f;

    if (rows == ROWS) {
        // ---------- A: logits -> registers (loads stay in flight) ----------
        const vfloat4* lbase4 = (const vfloat4*)(logits + (size_t)row0 * NUM_CLASSES);
        vfloat4 lv[LVEC_ITERS];
        #pragma unroll
        for (int i = 0; i < LVEC_ITERS; ++i) lv[i] = lbase4[tid + i * 256];
        vfloat4 lvr = {0.f, 0.f, 0.f, 0.f};
        if (tid < LVEC_REM) lvr = lbase4[LVEC_ITERS * 256 + tid];

        // ---------- B: decode boxes ----------
        if (tid < ROWS) {
            lds_box[tid] = decode_clip(prop4[row0 + tid], box_reg4[row0 + tid], wmax, hmax);
        }
        lds_barrier();                // LDS visible; global loads still pending

        // ---------- C: box stores (independent of pending loads) ----------
        vfloat4* bdst = (vfloat4*)out_boxes + (size_t)row0 * NUM_CLASSES;
        #pragma unroll
        for (int i = 0; i < BOX_ITERS; ++i) {
            const int j = tid + i * 256;
            const int rloc = (int)(((unsigned)j * 12946u) >> 20);   // j/81, exact j<20971
            const float4 bx = lds_box[rloc];
            vfloat4 bv = { bx.x, bx.y, bx.z, bx.w };
            __builtin_nontemporal_store(bv, bdst + j);
        }
        if (tid < BOX_REM) {
            const int j = BOX_ITERS * 256 + tid;
            const int rloc = (int)(((unsigned)j * 12946u) >> 20);
            const float4 bx = lds_box[rloc];
            vfloat4 bv = { bx.x, bx.y, bx.z, bx.w };
            __builtin_nontemporal_store(bv, bdst + j);
        }

        // ---------- D: registers -> LDS (compiler waits vmcnt per use) ----------
        #pragma unroll
        for (int i = 0; i < LVEC_ITERS; ++i) lds4[tid + i * 256] = lv[i];
        if (tid < LVEC_REM) lds4[LVEC_ITERS * 256 + tid] = lvr;
        lds_barrier();

        // ---------- E: softmax, 4 lanes per row ----------
        {
            const int sub = tid & 3;
            const int rl  = tid >> 2;          // 0..63
            float* rowv = lds_val + rl * NUM_CLASSES;

            float v[21];
            float m = -INFINITY;
            #pragma unroll
            for (int i = 0; i < 21; ++i) {
                const int k = sub + i * 4;
                if (k < NUM_CLASSES) { v[i] = rowv[k]; m = fmaxf(m, v[i]); }
                else                 { v[i] = -INFINITY; }
            }
            m = fmaxf(m, __shfl_xor(m, 1));
            m = fmaxf(m, __shfl_xor(m, 2));

            float s = 0.0f;
            #pragma unroll
            for (int i = 0; i < 21; ++i) {
                const int k = sub + i * 4;
                if (k < NUM_CLASSES) { v[i] = __expf(v[i] - m); s += v[i]; }
            }
            s += __shfl_xor(s, 1);
            s += __shfl_xor(s, 2);

            const float inv = 1.0f / s;
            #pragma unroll
            for (int i = 0; i < 21; ++i) {
                const int k = sub + i * 4;
                if (k < NUM_CLASSES) rowv[k] = v[i] * inv;   // own slots: no race
            }
        }
        lds_barrier();

        // ---------- F: score stores ----------
        vfloat4* sdst = (vfloat4*)(out_scores + (size_t)row0 * NUM_CLASSES);
        #pragma unroll
        for (int i = 0; i < LVEC_ITERS; ++i)
            __builtin_nontemporal_store(lds4[tid + i * 256], sdst + tid + i * 256);
        if (tid < LVEC_REM)
            __builtin_nontemporal_store(lds4[LVEC_ITERS * 256 + tid],
                                        sdst + LVEC_ITERS * 256 + tid);
    } else {
        // ---------- tail block: simple, correct, full barriers ----------
        const int elems = rows * NUM_CLASSES;
        const float* lbase = logits + (size_t)row0 * NUM_CLASSES;
        for (int e = tid; e < elems; e += 256) lds_val[e] = lbase[e];
        if (tid < rows) {
            lds_box[tid] = decode_clip(prop4[row0 + tid], box_reg4[row0 + tid], wmax, hmax);
        }
        __syncthreads();

        const int sub = tid & 3;
        const int rl  = tid >> 2;
        if (rl < rows) {
            float* rowv = lds_val + rl * NUM_CLASSES;
            float v[21];
            float m = -INFINITY;
            #pragma unroll
            for (int i = 0; i < 21; ++i) {
                const int k = sub + i * 4;
                if (k < NUM_CLASSES) { v[i] = rowv[k]; m = fmaxf(m, v[i]); }
                else                 { v[i] = -INFINITY; }
            }
            m = fmaxf(m, __shfl_xor(m, 1));
            m = fmaxf(m, __shfl_xor(m, 2));
            float s = 0.0f;
            #pragma unroll
            for (int i = 0; i < 21; ++i) {
                const int k = sub + i * 4;
                if (k < NUM_CLASSES) { v[i] = __expf(v[i] - m); s += v[i]; }
            }
            s += __shfl_xor(s, 1);
            s += __shfl_xor(s, 2);
            const float inv = 1.0f / s;
            #pragma unroll
            for (int i = 0; i < 21; ++i) {
                const int k = sub + i * 4;
                if (k < NUM_CLASSES) rowv[k] = v[i] * inv;
            }
        }
        __syncthreads();

        float* sdst = out_scores + (size_t)row0 * NUM_CLASSES;
        for (int e = tid; e < elems; e += 256) sdst[e] = lds_val[e];
        float4* bdst = (float4*)out_boxes + (size_t)row0 * NUM_CLASSES;
        for (int j = tid; j < elems; j += 256) {
            const int rloc = (int)(((unsigned)j * 12946u) >> 20);
            bdst[j] = lds_box[rloc];
        }
    }
}

extern "C" void kernel_launch(void* const* d_in, const int* in_sizes, int n_in,
                              void* d_out, int out_size, void* d_ws, size_t ws_size,
                              hipStream_t stream) {
    const float* logits   = (const float*)d_in[0];
    const float4* boxreg4 = (const float4*)d_in[1];
    const float4* prop4   = (const float4*)d_in[2];
    const int*   img_w_p  = (const int*)d_in[3];
    const int*   img_h_p  = (const int*)d_in[4];

    const int N = in_sizes[1] / 4;  // box_regression is (N,4)

    float* out_boxes  = (float*)d_out;
    float* out_scores = out_boxes + (size_t)N * NUM_CLASSES * 4;

    const int blocks = (N + ROWS - 1) / ROWS;
    fused_kernel<<<blocks, 256, 0, stream>>>(
        logits, boxreg4, prop4, img_w_p, img_h_p, out_boxes, out_scores, N);
}

// Round 4
// 484.818 us; speedup vs baseline: 1.0213x; 1.0213x over previous
//
#include <hip/hip_runtime.h>
#include <math.h>

#define NUM_CLASSES 81

typedef float vfloat4 __attribute__((ext_vector_type(4)));

__device__ __forceinline__ float4 decode_clip(const float4 b, const float4 r,
                                              const float wmax, const float hmax)
{
    const float BBOX_XFORM_CLIP = 4.135166556742356f; // log(1000/16)
    const float w  = b.z - b.x + 1.0f;
    const float h  = b.w - b.y + 1.0f;
    const float cx = b.x + 0.5f * w;
    const float cy = b.y + 0.5f * h;
    const float dx = r.x * 0.1f;
    const float dy = r.y * 0.1f;
    const float dw = fminf(r.z * 0.2f, BBOX_XFORM_CLIP);
    const float dh = fminf(r.w * 0.2f, BBOX_XFORM_CLIP);
    const float px = dx * w + cx;
    const float py = dy * h + cy;
    const float pw = expf(dw) * w;
    const float ph = expf(dh) * h;
    const float x1 = fminf(fmaxf(px - 0.5f * pw, 0.0f), wmax);
    const float y1 = fminf(fmaxf(py - 0.5f * ph, 0.0f), hmax);
    const float x2 = fminf(fmaxf(px + 0.5f * pw - 1.0f, 0.0f), wmax);
    const float y2 = fminf(fmaxf(py + 0.5f * ph - 1.0f, 0.0f), hmax);
    return make_float4(x1, y1, x2, y2);
}

// ============================================================================
// Kernel 1: boxes — pure streaming write of the 81x-tiled decoded boxes.
// 64 rows/block, 256 threads. Decode into LDS (wave 0 only), one barrier,
// then 20 fully-unrolled contiguous nontemporal float4 stores per thread.
// ============================================================================
#define BROWS  64
#define BELEMS (BROWS * NUM_CLASSES)   // 5184 float4 outputs per block
#define BITERS (BELEMS / 256)          // 20 full iterations; tail = 64

__global__ __launch_bounds__(256) void boxes_kernel(
    const float4* __restrict__ box_reg4,
    const float4* __restrict__ prop4,
    const int* __restrict__ img_w_p,
    const int* __restrict__ img_h_p,
    float* __restrict__ out_boxes,
    int N)
{
    __shared__ float4 lds_box[BROWS];
    const int tid  = threadIdx.x;
    const int row0 = blockIdx.x * BROWS;
    if (row0 >= N) return;
    const int rows = min(BROWS, N - row0);

    if (tid < rows) {
        const int row = row0 + tid;
        const float wmax = (float)(*img_w_p) - 1.0f;
        const float hmax = (float)(*img_h_p) - 1.0f;
        lds_box[tid] = decode_clip(prop4[row], box_reg4[row], wmax, hmax);
    }
    __syncthreads();

    vfloat4* dst = (vfloat4*)out_boxes + (size_t)row0 * NUM_CLASSES;
    if (rows == BROWS) {
        #pragma unroll
        for (int i = 0; i < BITERS; ++i) {
            const int j = tid + i * 256;
            // j < 5184: magic div by 81, exact for j < 20971
            const int rloc = (int)(((unsigned)j * 12946u) >> 20);
            const float4 bx = lds_box[rloc];
            vfloat4 bv = { bx.x, bx.y, bx.z, bx.w };
            __builtin_nontemporal_store(bv, dst + j);
        }
        // tail: last 64 float4s of the block's 5184
        if (tid < (BELEMS - BITERS * 256)) {
            const int j = BITERS * 256 + tid;
            const int rloc = (int)(((unsigned)j * 12946u) >> 20);
            const float4 bx = lds_box[rloc];
            vfloat4 bv = { bx.x, bx.y, bx.z, bx.w };
            __builtin_nontemporal_store(bv, dst + j);
        }
    } else {
        const int elems = rows * NUM_CLASSES;
        for (int i = 0; i <= BITERS; ++i) {
            const int j = tid + i * 256;
            if (j < elems) {
                const int rloc = (int)(((unsigned)j * 12946u) >> 20);
                const float4 bx = lds_box[rloc];
                vfloat4 bv = { bx.x, bx.y, bx.z, bx.w };
                __builtin_nontemporal_store(bv, dst + j);
            }
        }
    }
}

// ============================================================================
// Kernel 2: softmax scores — 16 rows/block, 256 threads; float4-coalesced
// LDS staging, 16 lanes/row shuffle softmax, float4 nontemporal writeback.
// ============================================================================
#define SROWS  16
#define SELEMS (SROWS * NUM_CLASSES)   // 1296 floats
#define SVECS  (SELEMS / 4)            // 324 float4s

__global__ __launch_bounds__(256) void scores_kernel(
    const float* __restrict__ logits,
    float* __restrict__ out_scores,
    int N)
{
    __shared__ vfloat4 lds4[SVECS];
    float* lds_val = (float*)lds4;
    const int tid  = threadIdx.x;
    const int row0 = blockIdx.x * SROWS;
    if (row0 >= N) return;
    const int rows = min(SROWS, N - row0);
    const bool full = (rows == SROWS);
    const int elems = rows * NUM_CLASSES;

    // ---------- stage logits ----------
    const float* lbase = logits + (size_t)row0 * NUM_CLASSES;
    if (full) {
        const vfloat4* lbase4 = (const vfloat4*)lbase;  // 1296*4B per block: 16B-aligned
        { int idx = tid;        lds4[idx] = lbase4[idx]; }
        { int idx = tid + 256;  if (idx < SVECS) lds4[idx] = lbase4[idx]; }
    } else {
        for (int i = 0; i < 6; ++i) {
            int e = tid + i * 256;
            if (e < elems) lds_val[e] = lbase[e];
        }
    }
    __syncthreads();

    // ---------- softmax: 16 lanes per row ----------
    const int sub = tid & 15;
    const int rl  = tid >> 4;
    if (rl < rows) {
        float* rowv = lds_val + rl * NUM_CLASSES;

        float v[6];
        float m = -INFINITY;
        #pragma unroll
        for (int i = 0; i < 6; ++i) {
            const int k = sub + i * 16;
            if (k < NUM_CLASSES) { v[i] = rowv[k]; m = fmaxf(m, v[i]); }
            else                 { v[i] = -INFINITY; }
        }
        #pragma unroll
        for (int off = 1; off <= 8; off <<= 1)
            m = fmaxf(m, __shfl_xor(m, off));

        float s = 0.0f;
        #pragma unroll
        for (int i = 0; i < 6; ++i) {
            const int k = sub + i * 16;
            if (k < NUM_CLASSES) { v[i] = __expf(v[i] - m); s += v[i]; }
        }
        #pragma unroll
        for (int off = 1; off <= 8; off <<= 1)
            s += __shfl_xor(s, off);

        const float inv = 1.0f / s;
        #pragma unroll
        for (int i = 0; i < 6; ++i) {
            const int k = sub + i * 16;
            if (k < NUM_CLASSES) rowv[k] = v[i] * inv;  // own slots only: no race
        }
    }
    __syncthreads();

    // ---------- writeback ----------
    float* sdst = out_scores + (size_t)row0 * NUM_CLASSES;
    if (full) {
        vfloat4* sdst4 = (vfloat4*)sdst;
        { int idx = tid;       __builtin_nontemporal_store(lds4[idx], sdst4 + idx); }
        { int idx = tid + 256; if (idx < SVECS)
                               __builtin_nontemporal_store(lds4[idx], sdst4 + idx); }
    } else {
        for (int i = 0; i < 6; ++i) {
            int e = tid + i * 256;
            if (e < elems) sdst[e] = lds_val[e];
        }
    }
}

extern "C" void kernel_launch(void* const* d_in, const int* in_sizes, int n_in,
                              void* d_out, int out_size, void* d_ws, size_t ws_size,
                              hipStream_t stream) {
    const float* logits   = (const float*)d_in[0];
    const float4* boxreg4 = (const float4*)d_in[1];
    const float4* prop4   = (const float4*)d_in[2];
    const int*   img_w_p  = (const int*)d_in[3];
    const int*   img_h_p  = (const int*)d_in[4];

    const int N = in_sizes[1] / 4;  // box_regression is (N,4)

    float* out_boxes  = (float*)d_out;
    float* out_scores = out_boxes + (size_t)N * NUM_CLASSES * 4;

    const int bblocks = (N + BROWS - 1) / BROWS;
    boxes_kernel<<<bblocks, 256, 0, stream>>>(
        boxreg4, prop4, img_w_p, img_h_p, out_boxes, N);

    const int sblocks = (N + SROWS - 1) / SROWS;
    scores_kernel<<<sblocks, 256, 0, stream>>>(logits, out_scores, N);
}